// Round 10
// baseline (1448.653 us; speedup 1.0000x reference)
//
#include <hip/hip_runtime.h>
#include <hip/hip_cooperative_groups.h>
#include <math.h>

namespace cg = cooperative_groups;

#define Bc 4
#define Nc 512
#define Pc 1024
#define Kc 20
#define MUL 64
#define NBc 20
#define HID 100
#define Tc 3
#define CUTc 4.0f
#define Ec (Nc * Kc)        /* 10240 */
#define PEc (Pc * Kc)       /* 20480 */
#define NA (Bc * Nc)        /* 2048 */
#define NP (Bc * Pc)        /* 4096 */
#define ET (Bc * Ec)        /* 40960 */
#define PET (Bc * PEc)      /* 81920 */
#define TBL 2048            /* w-table points over r in [0, RMAXT] */
#define RMAXT 6.5f          /* rbf(r) ~ 0 for r > 5 */
#define GRID 1024           /* cooperative grid: 4 blocks/CU x 256 CU */
#define TROWS 16            /* table rows per block */
#define TBLOCKS (6 * TBL / TROWS)  /* 768 */

__device__ __forceinline__ float silu_f(float x) { return x / (1.0f + __expf(-x)); }
__device__ __forceinline__ float lane_bcast_f(float v, int l) {
    return __int_as_float(__builtin_amdgcn_readlane(__float_as_int(v), l));
}

struct MegaArgs {
    const float *Wr1, *pWr1, *br1, *pbr1, *Wr2, *pWr2, *br2, *pbr2;
    const int *nodes; const float *Wemb;
    const float *apos, *ppos;
    const int *a_edges, *p_edges;
    const float *a_disp, *p_disp, *cell;
    const float *Wl, *pWl, *Wout;
    int *cnt_a, *cnt_p, *off_a, *cur_a, *off_p, *cur_p;
    float *rbuf_a; int *src_a; float *rbuf_p; int *src_p;
    float *h0row, *rep0, *rep1, *rep2, *wtab;
    float *out;
};

// ---------------------------------------------------------------------------
// Single cooperative mega-kernel: all phases, grid.sync() between deps.
// Phase 0: {w-table (768 blk, H through LDS) | cnt zero (4 blk) | embed (252)}
// 1: count  2: scan (2 blk)  3: geom  4-6: atom layers (512 blk)  7: probe3
// ---------------------------------------------------------------------------
__global__ __launch_bounds__(256, 4) void mega_kernel(MegaArgs A)
{
    cg::grid_group grid = cg::this_grid();
    __shared__ float lds[TROWS * HID];   // 6.4 KB; aliased per phase
    int bid = blockIdx.x;
    int t = threadIdx.x;
    const float step = CUTc / (NBc - 1);
    const float inv_sigma = (float)NBc / CUTc;
    const float scale = (float)TBL / RMAXT;
    const float isk = 0.22360679774997896f;  // 1/sqrt(20)

    // ---------------- Phase 0 ----------------
    if (bid < TBLOCKS) {
        int grow0 = bid * TROWS;              // global table row base
        int ly = grow0 / TBL;
        int t3 = (ly < 3) ? ly : ly - 3;
        const float* w1 = ((ly < 3) ? A.Wr1 : A.pWr1) + (size_t)t3 * NBc * HID;
        const float* b1 = ((ly < 3) ? A.br1 : A.pbr1) + (size_t)t3 * HID;
        const float* w2 = ((ly < 3) ? A.Wr2 : A.pWr2) + (size_t)t3 * HID * MUL;
        const float* b2 = ((ly < 3) ? A.br2 : A.pbr2) + (size_t)t3 * MUL;
        for (int id = t; id < TROWS * HID; id += 256) {
            int il = id / HID, j = id - il * HID;
            float r = (float)(grow0 % TBL + il) * (RMAXT / (float)TBL);
            float s = b1[j];
#pragma unroll
            for (int k = 0; k < NBc; ++k) {
                float tt = (r - k * step) * inv_sigma;
                s = fmaf(__expf(-tt * tt), w1[k * HID + j], s);
            }
            lds[il * HID + j] = silu_f(s);
        }
        __syncthreads();
        for (int o = t; o < TROWS * MUL; o += 256) {
            int il = o >> 6, c = o & 63;
            float acc = b2[c];
#pragma unroll 4
            for (int j = 0; j < HID; ++j)
                acc = fmaf(lds[il * HID + j], w2[(size_t)j * MUL + c], acc);
            A.wtab[(size_t)(grow0 + il) * MUL + c] = acc;
        }
    } else if (bid < TBLOCKS + 4) {
        int idx = (bid - TBLOCKS) * 256 + t;
        for (int i = idx; i < NA + NP; i += 4 * 256) A.cnt_a[i] = 0;  // contiguous cnt_a|cnt_p
    } else {
        int idx = (bid - TBLOCKS - 4) * 256 + t;
        for (int i = idx; i < NA * MUL; i += (GRID - TBLOCKS - 4) * 256) {
            int a = i >> 6, c = i & 63;
            A.h0row[i] = A.Wemb[A.nodes[a] * MUL + c];
        }
    }
    __threadfence(); grid.sync();

    // ---------------- Phase 1: count ----------------
    {
        int e = bid * 256 + t;
        if (e < ET) {
            atomicAdd(&A.cnt_a[A.a_edges[e * 2 + 1] + (e / Ec) * Nc], 1);
        } else if (e < ET + PET) {
            int el = e - ET;
            atomicAdd(&A.cnt_p[A.p_edges[el * 2 + 1] + (el / PEc) * Pc], 1);
        }
    }
    __threadfence(); grid.sync();

    // ---------------- Phase 2: scan (blocks 0,1) ----------------
    if (bid < 2) {
        const int* cnt; int* off; int* cur; int n;
        if (bid == 0) { cnt = A.cnt_a; off = A.off_a; cur = A.cur_a; n = NA; }
        else          { cnt = A.cnt_p; off = A.off_p; cur = A.cur_p; n = NP; }
        int* part = (int*)lds;
        int per = (n + 255) / 256;
        int lo = t * per, hi = min(lo + per, n);
        int s = 0;
        for (int i = lo; i < hi; ++i) s += cnt[i];
        part[t] = s;
        __syncthreads();
        if (t == 0) {
            int run = 0;
            for (int i = 0; i < 256; ++i) { int v = part[i]; part[i] = run; run += v; }
            off[n] = run;
        }
        __syncthreads();
        int run = part[t];
        for (int i = lo; i < hi; ++i) { off[i] = run; cur[i] = run; run += cnt[i]; }
    }
    __threadfence(); grid.sync();

    // ---------------- Phase 3: geom ----------------
    {
        int e = bid * 256 + t;
        if (e < ET + PET) {
            const int* edges; const float* displ; const float* pdst;
            int* cur; float* rout; int* sout;
            int el, Eper, dst_stride;
            if (e < ET) {
                el = e; edges = A.a_edges; displ = A.a_disp; pdst = A.apos;
                Eper = Ec; dst_stride = Nc; cur = A.cur_a; rout = A.rbuf_a; sout = A.src_a;
            } else {
                el = e - ET; edges = A.p_edges; displ = A.p_disp; pdst = A.ppos;
                Eper = PEc; dst_stride = Pc; cur = A.cur_p; rout = A.rbuf_p; sout = A.src_p;
            }
            int b = el / Eper;
            int sg = edges[el * 2 + 0] + b * Nc;
            int dg = edges[el * 2 + 1] + b * dst_stride;
            const float* C = A.cell + b * 9;
            float d0 = displ[el * 3 + 0], d1 = displ[el * 3 + 1], d2 = displ[el * 3 + 2];
            float dx = d0 * C[0] + d1 * C[3] + d2 * C[6];
            float dy = d0 * C[1] + d1 * C[4] + d2 * C[7];
            float dz = d0 * C[2] + d1 * C[5] + d2 * C[8];
            float vx = pdst[dg * 3 + 0] - (A.apos[sg * 3 + 0] + dx);
            float vy = pdst[dg * 3 + 1] - (A.apos[sg * 3 + 1] + dy);
            float vz = pdst[dg * 3 + 2] - (A.apos[sg * 3 + 2] + dz);
            float r = sqrtf(vx * vx + vy * vy + vz * vz);
            int pos = atomicAdd(&cur[dg], 1);
            rout[pos] = r;
            sout[pos] = sg;
        }
    }
    __threadfence(); grid.sync();

    // ---------------- Phases 4-6: atom layers ----------------
    int c = t & 63;
    int w = t >> 6;
    float* tile = lds;  // [4][64]
    for (int tl = 0; tl < Tc; ++tl) {
        const float* hsrc = (tl == 0) ? A.h0row : ((tl == 1) ? A.rep0 : A.rep1);
        float* outb = (tl == 0) ? A.rep0 : ((tl == 1) ? A.rep1 : A.rep2);
        const float* wtab = A.wtab + (size_t)tl * TBL * MUL;
        const float* Wl0 = A.Wl + (size_t)tl * 3 * MUL * MUL;
        if (bid < NA / 4) {
            int n = bid * 4 + w;
            int e0 = A.off_a[n], e1 = A.off_a[n + 1];
            float acc = 0.0f;
            for (int bse = e0; bse < e1; bse += 64) {
                int mm = min(e1 - bse, 64);
                float rvec = 0.0f; int svec = 0;
                if (c < mm) { rvec = A.rbuf_a[bse + c]; svec = A.src_a[bse + c]; }
#pragma unroll 4
                for (int p = 0; p < mm; ++p) {
                    float rr = lane_bcast_f(rvec, p);
                    int sg = __builtin_amdgcn_readlane(svec, p);
                    float x = fminf(rr * scale, (float)TBL - 1.001f);
                    int i0 = (int)x;
                    float f = x - (float)i0;
                    const float* tp = wtab + (size_t)i0 * MUL;
                    float w0 = tp[c];
                    float w1 = tp[MUL + c];
                    float wv = fmaf(w1 - w0, f, w0);
                    acc = fmaf(hsrc[(size_t)sg * MUL + c], wv, acc);
                }
            }
            acc *= isk;
            tile[w * 64 + c] = acc;            // same-wave LDS RAW
            float u = 0.0f;
#pragma unroll
            for (int k4 = 0; k4 < 16; ++k4) {
                float4 av = *(const float4*)&tile[w * 64 + k4 * 4];
                u = fmaf(av.x, Wl0[(k4 * 4 + 0) * 64 + c], u);
                u = fmaf(av.y, Wl0[(k4 * 4 + 1) * 64 + c], u);
                u = fmaf(av.z, Wl0[(k4 * 4 + 2) * 64 + c], u);
                u = fmaf(av.w, Wl0[(k4 * 4 + 3) * 64 + c], u);
            }
            outb[(size_t)n * MUL + c] = hsrc[(size_t)n * MUL + c] + silu_f(u);
        }
        __threadfence(); grid.sync();
    }

    // ---------------- Phase 7: probe3 + readout ----------------
    {
        int n = bid * 4 + w;                   // GRID*4 == NP exactly
        int e0 = A.off_p[n], e1 = A.off_p[n + 1];
        float acc0 = 0.0f, acc1 = 0.0f, acc2 = 0.0f;
        const float* wt0 = A.wtab + (size_t)3 * TBL * MUL;
        const float* wt1 = wt0 + (size_t)TBL * MUL;
        const float* wt2 = wt1 + (size_t)TBL * MUL;
        for (int bse = e0; bse < e1; bse += 64) {
            int mm = min(e1 - bse, 64);
            float rvec = 0.0f; int svec = 0;
            if (c < mm) { rvec = A.rbuf_p[bse + c]; svec = A.src_p[bse + c]; }
#pragma unroll 2
            for (int p = 0; p < mm; ++p) {
                float rr = lane_bcast_f(rvec, p);
                int sg = __builtin_amdgcn_readlane(svec, p);
                float x = fminf(rr * scale, (float)TBL - 1.001f);
                int i0 = (int)x;
                float f = x - (float)i0;
                size_t rowo = (size_t)i0 * MUL + c;
                float wv0 = fmaf(wt0[rowo + MUL] - wt0[rowo], f, wt0[rowo]);
                float wv1 = fmaf(wt1[rowo + MUL] - wt1[rowo], f, wt1[rowo]);
                float wv2 = fmaf(wt2[rowo + MUL] - wt2[rowo], f, wt2[rowo]);
                size_t so = (size_t)sg * MUL + c;
                acc0 = fmaf(A.rep0[so], wv0, acc0);
                acc1 = fmaf(A.rep1[so], wv1, acc1);
                acc2 = fmaf(A.rep2[so], wv2, acc2);
            }
        }
        float res = 0.0f;
        float accs[3] = {acc0, acc1, acc2};
#pragma unroll
        for (int tt = 0; tt < 3; ++tt) {
            tile[w * 64 + c] = accs[tt] * isk;   // same-wave LDS RAW
            const float* W = A.pWl + (size_t)tt * 3 * MUL * MUL;  // l0 slice
            float u = 0.0f;
#pragma unroll
            for (int k4 = 0; k4 < 16; ++k4) {
                float4 av = *(const float4*)&tile[w * 64 + k4 * 4];
                u = fmaf(av.x, W[(k4 * 4 + 0) * 64 + c], u);
                u = fmaf(av.y, W[(k4 * 4 + 1) * 64 + c], u);
                u = fmaf(av.z, W[(k4 * 4 + 2) * 64 + c], u);
                u = fmaf(av.w, W[(k4 * 4 + 3) * 64 + c], u);
            }
            res += silu_f(u);
        }
        float v = res * A.Wout[c];
#pragma unroll
        for (int o = 32; o > 0; o >>= 1) v += __shfl_down(v, o, 64);
        if (c == 0) A.out[n] = v;
    }
}

// ===========================================================================
// Fallback path (round-9 kernels, launched separately) if cooperative launch
// is unavailable in this environment.
// ===========================================================================
#define HBLOCKS (6 * TBL * HID / 256)
#define ZBLOCKS 8
#define EBLOCKS 32

__global__ __launch_bounds__(256) void front_kernel(
    const float* __restrict__ Wr1, const float* __restrict__ pWr1,
    const float* __restrict__ br1, const float* __restrict__ pbr1,
    const int* __restrict__ nodes, const float* __restrict__ Wemb,
    int* __restrict__ cnt_both, float* __restrict__ h0row,
    float* __restrict__ H)
{
    int bid = blockIdx.x;
    int t = threadIdx.x;
    if (bid < HBLOCKS) {
        int id = bid * 256 + t;
        int j = id % HID;
        int rest = id / HID;
        int i = rest % TBL;
        int ly = rest / TBL;
        int t3 = (ly < 3) ? ly : ly - 3;
        const float* w1 = ((ly < 3) ? Wr1 : pWr1) + (size_t)t3 * NBc * HID;
        const float* b1 = ((ly < 3) ? br1 : pbr1) + (size_t)t3 * HID;
        float r = (float)i * (RMAXT / (float)TBL);
        const float step = CUTc / (NBc - 1);
        const float inv_sigma = (float)NBc / CUTc;
        float s = b1[j];
#pragma unroll
        for (int k = 0; k < NBc; ++k) {
            float tt = (r - k * step) * inv_sigma;
            s = fmaf(__expf(-tt * tt), w1[k * HID + j], s);
        }
        H[id] = silu_f(s);
    } else if (bid < HBLOCKS + ZBLOCKS) {
        int idx = (bid - HBLOCKS) * 256 + t;
        for (int i = idx; i < NA + NP; i += ZBLOCKS * 256) cnt_both[i] = 0;
    } else {
        int idx = (bid - HBLOCKS - ZBLOCKS) * 256 + t;
        for (int i = idx; i < NA * MUL; i += EBLOCKS * 256) {
            int a = i >> 6, c = i & 63;
            h0row[i] = Wemb[nodes[a] * MUL + c];
        }
    }
}

__global__ __launch_bounds__(256) void w2_kernel(
    const float* __restrict__ H,
    const float* __restrict__ Wr2, const float* __restrict__ pWr2,
    const float* __restrict__ br2, const float* __restrict__ pbr2,
    float* __restrict__ wtab)
{
    int c = threadIdx.x & 63;
    int wid = __builtin_amdgcn_readfirstlane(blockIdx.x * 4 + (threadIdx.x >> 6));
    int ly = wid / TBL;
    int t3 = (ly < 3) ? ly : ly - 3;
    const float* w2 = ((ly < 3) ? Wr2 : pWr2) + (size_t)t3 * HID * MUL;
    const float* b2 = ((ly < 3) ? br2 : pbr2) + (size_t)t3 * MUL;
    const float* h = H + (size_t)wid * HID;
    float acc = b2[c];
#pragma unroll 4
    for (int j = 0; j < HID; ++j)
        acc = fmaf(h[j], w2[(size_t)j * MUL + c], acc);
    wtab[(size_t)wid * MUL + c] = acc;
}

__global__ void count_all_kernel(const int* __restrict__ a_edges,
                                 const int* __restrict__ p_edges,
                                 int* __restrict__ cnt_a, int* __restrict__ cnt_p)
{
    int e = blockIdx.x * 256 + threadIdx.x;
    if (e >= ET + PET) return;
    if (e < ET) {
        atomicAdd(&cnt_a[a_edges[e * 2 + 1] + (e / Ec) * Nc], 1);
    } else {
        int el = e - ET;
        atomicAdd(&cnt_p[p_edges[el * 2 + 1] + (el / PEc) * Pc], 1);
    }
}

__global__ void scan_all_kernel(const int* __restrict__ cnt_a, int* __restrict__ off_a,
                                int* __restrict__ cur_a,
                                const int* __restrict__ cnt_p, int* __restrict__ off_p,
                                int* __restrict__ cur_p)
{
    const int* cnt; int* off; int* cur; int n;
    if (blockIdx.x == 0) { cnt = cnt_a; off = off_a; cur = cur_a; n = NA; }
    else                 { cnt = cnt_p; off = off_p; cur = cur_p; n = NP; }
    __shared__ int part[256];
    int t = threadIdx.x;
    int per = (n + 255) / 256;
    int lo = t * per, hi = min(lo + per, n);
    int s = 0;
    for (int i = lo; i < hi; ++i) s += cnt[i];
    part[t] = s;
    __syncthreads();
    if (t == 0) {
        int run = 0;
        for (int i = 0; i < 256; ++i) { int v = part[i]; part[i] = run; run += v; }
        off[n] = run;
    }
    __syncthreads();
    int run = part[t];
    for (int i = lo; i < hi; ++i) { off[i] = run; cur[i] = run; run += cnt[i]; }
}

__global__ void geom_all_kernel(const float* __restrict__ apos,
                                const float* __restrict__ ppos,
                                const int* __restrict__ a_edges,
                                const int* __restrict__ p_edges,
                                const float* __restrict__ a_disp,
                                const float* __restrict__ p_disp,
                                const float* __restrict__ cell,
                                int* __restrict__ cur_a, int* __restrict__ cur_p,
                                float* __restrict__ r_a, float* __restrict__ r_p,
                                int* __restrict__ s_a, int* __restrict__ s_p)
{
    int e = blockIdx.x * 256 + threadIdx.x;
    if (e >= ET + PET) return;
    const int* edges; const float* displ; const float* pdst;
    int* cur; float* rout; int* sout;
    int el, Eper, dst_stride;
    if (e < ET) {
        el = e; edges = a_edges; displ = a_disp; pdst = apos;
        Eper = Ec; dst_stride = Nc; cur = cur_a; rout = r_a; sout = s_a;
    } else {
        el = e - ET; edges = p_edges; displ = p_disp; pdst = ppos;
        Eper = PEc; dst_stride = Pc; cur = cur_p; rout = r_p; sout = s_p;
    }
    int b = el / Eper;
    int sg = edges[el * 2 + 0] + b * Nc;
    int dg = edges[el * 2 + 1] + b * dst_stride;
    const float* C = cell + b * 9;
    float d0 = displ[el * 3 + 0], d1 = displ[el * 3 + 1], d2 = displ[el * 3 + 2];
    float dx = d0 * C[0] + d1 * C[3] + d2 * C[6];
    float dy = d0 * C[1] + d1 * C[4] + d2 * C[7];
    float dz = d0 * C[2] + d1 * C[5] + d2 * C[8];
    float vx = pdst[dg * 3 + 0] - (apos[sg * 3 + 0] + dx);
    float vy = pdst[dg * 3 + 1] - (apos[sg * 3 + 1] + dy);
    float vz = pdst[dg * 3 + 2] - (apos[sg * 3 + 2] + dz);
    float r = sqrtf(vx * vx + vy * vy + vz * vz);
    int pos = atomicAdd(&cur[dg], 1);
    rout[pos] = r;
    sout[pos] = sg;
}

__global__ __launch_bounds__(256) void layer_kernel(
    const float* __restrict__ hsrc, const float* __restrict__ base,
    float* __restrict__ outb,
    const int* __restrict__ off, const int* __restrict__ srcg,
    const float* __restrict__ rbuf, const float* __restrict__ wtab,
    const float* __restrict__ Wl0, int n_out)
{
    __shared__ float tile[4][64];
    int c = threadIdx.x & 63;
    int w = threadIdx.x >> 6;
    int n = blockIdx.x * 4 + w;
    if (n >= n_out) return;

    int e0 = off[n], e1 = off[n + 1];
    float acc = 0.0f;
    const float scale = (float)TBL / RMAXT;
    for (int bse = e0; bse < e1; bse += 64) {
        int mm = min(e1 - bse, 64);
        float rvec = 0.0f; int svec = 0;
        if (c < mm) { rvec = rbuf[bse + c]; svec = srcg[bse + c]; }
#pragma unroll 4
        for (int p = 0; p < mm; ++p) {
            float rr = lane_bcast_f(rvec, p);
            int sg = __builtin_amdgcn_readlane(svec, p);
            float x = fminf(rr * scale, (float)TBL - 1.001f);
            int i0 = (int)x;
            float f = x - (float)i0;
            const float* tp = wtab + (size_t)i0 * MUL;
            float w0 = tp[c];
            float w1 = tp[MUL + c];
            float wv = fmaf(w1 - w0, f, w0);
            acc = fmaf(hsrc[(size_t)sg * MUL + c], wv, acc);
        }
    }
    acc *= 0.22360679774997896f;

    tile[w][c] = acc;
    float u = 0.0f;
#pragma unroll
    for (int k4 = 0; k4 < 16; ++k4) {
        float4 av = *(const float4*)&tile[w][k4 * 4];
        u = fmaf(av.x, Wl0[(k4 * 4 + 0) * 64 + c], u);
        u = fmaf(av.y, Wl0[(k4 * 4 + 1) * 64 + c], u);
        u = fmaf(av.z, Wl0[(k4 * 4 + 2) * 64 + c], u);
        u = fmaf(av.w, Wl0[(k4 * 4 + 3) * 64 + c], u);
    }
    outb[(size_t)n * MUL + c] = base[(size_t)n * MUL + c] + silu_f(u);
}

__global__ __launch_bounds__(256) void probe3_kernel(
    const float* __restrict__ rep0, const float* __restrict__ rep1,
    const float* __restrict__ rep2,
    const int* __restrict__ off, const int* __restrict__ srcg,
    const float* __restrict__ rbuf, const float* __restrict__ wtab,
    const float* __restrict__ pWl, const float* __restrict__ Wout,
    float* __restrict__ out)
{
    __shared__ float tile[4][64];
    int c = threadIdx.x & 63;
    int w = threadIdx.x >> 6;
    int n = blockIdx.x * 4 + w;

    int e0 = off[n], e1 = off[n + 1];
    float acc0 = 0.0f, acc1 = 0.0f, acc2 = 0.0f;
    const float scale = (float)TBL / RMAXT;
    const float* wt0 = wtab;
    const float* wt1 = wtab + (size_t)TBL * MUL;
    const float* wt2 = wtab + (size_t)2 * TBL * MUL;
    for (int bse = e0; bse < e1; bse += 64) {
        int mm = min(e1 - bse, 64);
        float rvec = 0.0f; int svec = 0;
        if (c < mm) { rvec = rbuf[bse + c]; svec = srcg[bse + c]; }
#pragma unroll 2
        for (int p = 0; p < mm; ++p) {
            float rr = lane_bcast_f(rvec, p);
            int sg = __builtin_amdgcn_readlane(svec, p);
            float x = fminf(rr * scale, (float)TBL - 1.001f);
            int i0 = (int)x;
            float f = x - (float)i0;
            size_t rowo = (size_t)i0 * MUL + c;
            float wv0 = fmaf(wt0[rowo + MUL] - wt0[rowo], f, wt0[rowo]);
            float wv1 = fmaf(wt1[rowo + MUL] - wt1[rowo], f, wt1[rowo]);
            float wv2 = fmaf(wt2[rowo + MUL] - wt2[rowo], f, wt2[rowo]);
            size_t so = (size_t)sg * MUL + c;
            acc0 = fmaf(rep0[so], wv0, acc0);
            acc1 = fmaf(rep1[so], wv1, acc1);
            acc2 = fmaf(rep2[so], wv2, acc2);
        }
    }
    const float isk = 0.22360679774997896f;
    float res = 0.0f;
    float accs[3] = {acc0, acc1, acc2};
#pragma unroll
    for (int t = 0; t < 3; ++t) {
        tile[w][c] = accs[t] * isk;
        const float* W = pWl + (size_t)t * 3 * MUL * MUL;
        float u = 0.0f;
#pragma unroll
        for (int k4 = 0; k4 < 16; ++k4) {
            float4 av = *(const float4*)&tile[w][k4 * 4];
            u = fmaf(av.x, W[(k4 * 4 + 0) * 64 + c], u);
            u = fmaf(av.y, W[(k4 * 4 + 1) * 64 + c], u);
            u = fmaf(av.z, W[(k4 * 4 + 2) * 64 + c], u);
            u = fmaf(av.w, W[(k4 * 4 + 3) * 64 + c], u);
        }
        res += silu_f(u);
    }

    float v = res * Wout[c];
#pragma unroll
    for (int o = 32; o > 0; o >>= 1) v += __shfl_down(v, o, 64);
    if (c == 0) out[n] = v;
}

// ---------------------------------------------------------------------------
extern "C" void kernel_launch(void* const* d_in, const int* in_sizes, int n_in,
                              void* d_out, int out_size, void* d_ws, size_t ws_size,
                              hipStream_t stream)
{
    const float* atom_xyz  = (const float*)d_in[0];
    const float* a_disp    = (const float*)d_in[1];
    const float* cell      = (const float*)d_in[2];
    const float* probe_xyz = (const float*)d_in[3];
    const float* p_disp    = (const float*)d_in[4];
    const float* W_embed   = (const float*)d_in[5];
    const float* Wr1       = (const float*)d_in[6];
    const float* br1       = (const float*)d_in[7];
    const float* Wr2       = (const float*)d_in[8];
    const float* br2       = (const float*)d_in[9];
    const float* Wl        = (const float*)d_in[10];
    const float* pWr1      = (const float*)d_in[12];
    const float* pbr1      = (const float*)d_in[13];
    const float* pWr2      = (const float*)d_in[14];
    const float* pbr2      = (const float*)d_in[15];
    const float* pWl       = (const float*)d_in[16];
    const float* W_out     = (const float*)d_in[18];
    const int*   atom_edges  = (const int*)d_in[19];
    const int*   probe_edges = (const int*)d_in[20];
    const int*   nodes       = (const int*)d_in[21];
    float* out = (float*)d_out;

    char* w = (char*)d_ws;
    auto alloc = [&](size_t bytes) -> void* {
        void* r = (void*)w;
        w += (bytes + 255) & ~(size_t)255;
        return r;
    };
    int*   cnt_both = (int*)alloc((size_t)(NA + NP) * 4);
    int*   cnt_a  = cnt_both;
    int*   cnt_p  = cnt_both + NA;
    int*   off_a  = (int*)alloc((size_t)(NA + 1) * 4);
    int*   cur_a  = (int*)alloc((size_t)NA * 4);
    int*   off_p  = (int*)alloc((size_t)(NP + 1) * 4);
    int*   cur_p  = (int*)alloc((size_t)NP * 4);
    float* rbuf_a = (float*)alloc((size_t)ET * 4);
    int*   src_a  = (int*)alloc((size_t)ET * 4);
    float* rbuf_p = (float*)alloc((size_t)PET * 4);
    int*   src_p  = (int*)alloc((size_t)PET * 4);
    float* h0row  = (float*)alloc((size_t)NA * MUL * 4);
    float* rep0   = (float*)alloc((size_t)NA * MUL * 4);
    float* rep1   = (float*)alloc((size_t)NA * MUL * 4);
    float* rep2   = (float*)alloc((size_t)NA * MUL * 4);
    float* wtab   = (float*)alloc((size_t)6 * TBL * MUL * 4);
    float* Hbuf   = (float*)alloc((size_t)6 * TBL * HID * 4);  // fallback only

    MegaArgs A;
    A.Wr1 = Wr1; A.pWr1 = pWr1; A.br1 = br1; A.pbr1 = pbr1;
    A.Wr2 = Wr2; A.pWr2 = pWr2; A.br2 = br2; A.pbr2 = pbr2;
    A.nodes = nodes; A.Wemb = W_embed;
    A.apos = atom_xyz; A.ppos = probe_xyz;
    A.a_edges = atom_edges; A.p_edges = probe_edges;
    A.a_disp = a_disp; A.p_disp = p_disp; A.cell = cell;
    A.Wl = Wl; A.pWl = pWl; A.Wout = W_out;
    A.cnt_a = cnt_a; A.cnt_p = cnt_p;
    A.off_a = off_a; A.cur_a = cur_a; A.off_p = off_p; A.cur_p = cur_p;
    A.rbuf_a = rbuf_a; A.src_a = src_a; A.rbuf_p = rbuf_p; A.src_p = src_p;
    A.h0row = h0row; A.rep0 = rep0; A.rep1 = rep1; A.rep2 = rep2;
    A.wtab = wtab; A.out = out;

    void* kargs[] = { (void*)&A };
    hipError_t err = hipLaunchCooperativeKernel((const void*)mega_kernel,
                                                dim3(GRID), dim3(256),
                                                kargs, 0, stream);
    if (err == hipSuccess) return;
    (void)hipGetLastError();  // clear; fall back to the 9-launch path

    front_kernel<<<HBLOCKS + ZBLOCKS + EBLOCKS, 256, 0, stream>>>(
        Wr1, pWr1, br1, pbr1, nodes, W_embed, cnt_both, h0row, Hbuf);
    w2_kernel<<<6 * TBL / 4, 256, 0, stream>>>(Hbuf, Wr2, pWr2, br2, pbr2, wtab);
    count_all_kernel<<<(ET + PET + 255) / 256, 256, 0, stream>>>(
        atom_edges, probe_edges, cnt_a, cnt_p);
    scan_all_kernel<<<2, 256, 0, stream>>>(cnt_a, off_a, cur_a, cnt_p, off_p, cur_p);
    geom_all_kernel<<<(ET + PET + 255) / 256, 256, 0, stream>>>(
        atom_xyz, probe_xyz, atom_edges, probe_edges, a_disp, p_disp, cell,
        cur_a, cur_p, rbuf_a, rbuf_p, src_a, src_p);
    const float* hprev = h0row;
    float* reps[3] = {rep0, rep1, rep2};
    for (int t = 0; t < Tc; ++t) {
        layer_kernel<<<NA / 4, 256, 0, stream>>>(
            hprev, hprev, reps[t], off_a, src_a, rbuf_a,
            wtab + (size_t)t * TBL * MUL,
            Wl + (size_t)t * 3 * MUL * MUL, NA);
        hprev = reps[t];
    }
    probe3_kernel<<<NP / 4, 256, 0, stream>>>(
        rep0, rep1, rep2, off_p, src_p, rbuf_p,
        wtab + (size_t)3 * TBL * MUL, pWl, W_out, out);
}

// Round 11
// 85.885 us; speedup vs baseline: 16.8674x; 16.8674x over previous
//
#include <hip/hip_runtime.h>
#include <math.h>

#define Bc 4
#define Nc 512
#define Pc 1024
#define Kc 20
#define MUL 64
#define NBc 20
#define HID 100
#define Tc 3
#define CUTc 4.0f
#define Ec (Nc * Kc)        /* 10240 */
#define PEc (Pc * Kc)       /* 20480 */
#define NA (Bc * Nc)        /* 2048 */
#define NP (Bc * Pc)        /* 4096 */
#define ET (Bc * Ec)        /* 40960 */
#define PET (Bc * PEc)      /* 81920 */
#define TBL 2048            /* w-table points over r in [0, RMAXT] */
#define RMAXT 6.5f          /* rbf(r) ~ 0 for r > 5 */
#define CAP 64              /* bucket capacity per dst (max degree ~38 expected) */
#define TROWS 4             /* table rows per block in front_kernel */
#define TBLOCKS (6 * TBL / TROWS)  /* 3072 */
#define ZBLOCKS 8
#define EBLOCKS 32

__device__ __forceinline__ float silu_f(float x) { return x / (1.0f + __expf(-x)); }
__device__ __forceinline__ float lane_bcast_f(float v, int l) {
    return __int_as_float(__builtin_amdgcn_readlane(__float_as_int(v), l));
}

// ---------------------------------------------------------------------------
// Front kernel — all dep-free work, FULL grid width (round-8 lesson: never
// narrow the grid when fusing; round-10 lesson: never grid.sync on MI355X):
//   blocks [0, 3072):  w-table, TROWS=4 rows/block, hidden tile in LDS
//   blocks [3072, 3080): zero cnt arrays (runtime fill kernel costs 41us)
//   blocks [3080, 3112): embedding row 0
// ---------------------------------------------------------------------------
__global__ __launch_bounds__(256) void front_kernel(
    const float* __restrict__ Wr1, const float* __restrict__ pWr1,
    const float* __restrict__ br1, const float* __restrict__ pbr1,
    const float* __restrict__ Wr2, const float* __restrict__ pWr2,
    const float* __restrict__ br2, const float* __restrict__ pbr2,
    const int* __restrict__ nodes, const float* __restrict__ Wemb,
    int* __restrict__ cnt_both, float* __restrict__ h0row,
    float* __restrict__ wtab)
{
    __shared__ float Hs[TROWS * HID];   // 1.6 KB
    int bid = blockIdx.x;
    int t = threadIdx.x;

    if (bid < TBLOCKS) {
        int grow0 = bid * TROWS;          // global table row base (same ly for all 4)
        int ly = grow0 / TBL;
        int t3 = (ly < 3) ? ly : ly - 3;
        const float* w1 = ((ly < 3) ? Wr1 : pWr1) + (size_t)t3 * NBc * HID;
        const float* b1 = ((ly < 3) ? br1 : pbr1) + (size_t)t3 * HID;
        const float* w2 = ((ly < 3) ? Wr2 : pWr2) + (size_t)t3 * HID * MUL;
        const float* b2 = ((ly < 3) ? br2 : pbr2) + (size_t)t3 * MUL;
        const float step = CUTc / (NBc - 1);
        const float inv_sigma = (float)NBc / CUTc;

        // phase A: hidden tile (400 entries; ~2/thread)
        for (int id = t; id < TROWS * HID; id += 256) {
            int il = id / HID, j = id - il * HID;
            float r = (float)(grow0 % TBL + il) * (RMAXT / (float)TBL);
            float s = b1[j];
#pragma unroll
            for (int k = 0; k < NBc; ++k) {
                float tt = (r - k * step) * inv_sigma;
                s = fmaf(__expf(-tt * tt), w1[k * HID + j], s);
            }
            Hs[id] = silu_f(s);
        }
        __syncthreads();

        // phase B: 1 output/thread; wave covers one row -> LDS broadcast reads
        int il = t >> 6, c = t & 63;
        float acc = b2[c];
#pragma unroll 4
        for (int j = 0; j < HID; ++j)
            acc = fmaf(Hs[il * HID + j], w2[(size_t)j * MUL + c], acc);
        wtab[(size_t)(grow0 + il) * MUL + c] = acc;
    } else if (bid < TBLOCKS + ZBLOCKS) {
        int idx = (bid - TBLOCKS) * 256 + t;
        for (int i = idx; i < NA + NP; i += ZBLOCKS * 256) cnt_both[i] = 0;
    } else {
        int idx = (bid - TBLOCKS - ZBLOCKS) * 256 + t;
        for (int i = idx; i < NA * MUL; i += EBLOCKS * 256) {
            int a = i >> 6, c = i & 63;
            h0row[i] = Wemb[nodes[a] * MUL + c];
        }
    }
}

// ---------------------------------------------------------------------------
// Geometry + bucket fill (both graphs, one launch). Fixed CAP=64 slots/dst
// replaces the count->scan->fill CSR chain (2 fewer dependent launches).
// ---------------------------------------------------------------------------
__global__ void geom_kernel(const float* __restrict__ apos,
                            const float* __restrict__ ppos,
                            const int* __restrict__ a_edges,
                            const int* __restrict__ p_edges,
                            const float* __restrict__ a_disp,
                            const float* __restrict__ p_disp,
                            const float* __restrict__ cell,
                            int* __restrict__ cnt_a, int* __restrict__ cnt_p,
                            float* __restrict__ br_a, int* __restrict__ bs_a,
                            float* __restrict__ br_p, int* __restrict__ bs_p)
{
    int e = blockIdx.x * 256 + threadIdx.x;
    if (e >= ET + PET) return;
    const int* edges; const float* displ; const float* pdst;
    int* cnt; float* brout; int* bsout;
    int el, Eper, dst_stride;
    if (e < ET) {
        el = e; edges = a_edges; displ = a_disp; pdst = apos;
        Eper = Ec; dst_stride = Nc; cnt = cnt_a; brout = br_a; bsout = bs_a;
    } else {
        el = e - ET; edges = p_edges; displ = p_disp; pdst = ppos;
        Eper = PEc; dst_stride = Pc; cnt = cnt_p; brout = br_p; bsout = bs_p;
    }
    int b = el / Eper;
    int sg = edges[el * 2 + 0] + b * Nc;
    int dg = edges[el * 2 + 1] + b * dst_stride;
    const float* C = cell + b * 9;
    float d0 = displ[el * 3 + 0], d1 = displ[el * 3 + 1], d2 = displ[el * 3 + 2];
    float dx = d0 * C[0] + d1 * C[3] + d2 * C[6];
    float dy = d0 * C[1] + d1 * C[4] + d2 * C[7];
    float dz = d0 * C[2] + d1 * C[5] + d2 * C[8];
    float vx = pdst[dg * 3 + 0] - (apos[sg * 3 + 0] + dx);
    float vy = pdst[dg * 3 + 1] - (apos[sg * 3 + 1] + dy);
    float vz = pdst[dg * 3 + 2] - (apos[sg * 3 + 2] + dz);
    float r = sqrtf(vx * vx + vy * vy + vz * vz);
    int pos = atomicAdd(&cnt[dg], 1);
    if (pos < CAP) {
        brout[(size_t)dg * CAP + pos] = r;
        bsout[(size_t)dg * CAP + pos] = sg;
    }
}

// ---------------------------------------------------------------------------
// Atom conv layer (row-0 only), wave per node, 4 waves/block. Bucket row is
// exactly one wave-wide chunk: single lane-load + readlane broadcast loop.
// ---------------------------------------------------------------------------
__global__ __launch_bounds__(256) void layer_kernel(
    const float* __restrict__ hsrc,   // (n_src,64)
    float* __restrict__ outb,         // (n_out,64); base==hsrc (residual)
    const int* __restrict__ cnt,
    const float* __restrict__ brk, const int* __restrict__ bsk,
    const float* __restrict__ wtab,
    const float* __restrict__ Wl0)    // (64,64)
{
    __shared__ float tile[4][64];
    int c = threadIdx.x & 63;
    int w = threadIdx.x >> 6;
    int n = blockIdx.x * 4 + w;

    int m = min(cnt[n], CAP);
    float rvec = 0.0f; int svec = 0;
    if (c < m) { rvec = brk[(size_t)n * CAP + c]; svec = bsk[(size_t)n * CAP + c]; }
    float acc = 0.0f;
    const float scale = (float)TBL / RMAXT;
#pragma unroll 4
    for (int p = 0; p < m; ++p) {
        float rr = lane_bcast_f(rvec, p);
        int sg = __builtin_amdgcn_readlane(svec, p);
        float x = fminf(rr * scale, (float)TBL - 1.001f);
        int i0 = (int)x;
        float f = x - (float)i0;
        const float* tp = wtab + (size_t)i0 * MUL;
        float w0 = tp[c];
        float w1 = tp[MUL + c];
        float wv = fmaf(w1 - w0, f, w0);
        acc = fmaf(hsrc[(size_t)sg * MUL + c], wv, acc);
    }
    acc *= 0.22360679774997896f;  // 1/sqrt(20)

    tile[w][c] = acc;             // same-wave LDS RAW; no barrier needed
    float u = 0.0f;
#pragma unroll
    for (int k4 = 0; k4 < 16; ++k4) {
        float4 av = *(const float4*)&tile[w][k4 * 4];
        u = fmaf(av.x, Wl0[(k4 * 4 + 0) * 64 + c], u);
        u = fmaf(av.y, Wl0[(k4 * 4 + 1) * 64 + c], u);
        u = fmaf(av.z, Wl0[(k4 * 4 + 2) * 64 + c], u);
        u = fmaf(av.w, Wl0[(k4 * 4 + 3) * 64 + c], u);
    }
    outb[(size_t)n * MUL + c] = hsrc[(size_t)n * MUL + c] + silu_f(u);
}

// ---------------------------------------------------------------------------
// Fused probe pipeline: all 3 probe conv layers + readout in one kernel.
// ---------------------------------------------------------------------------
__global__ __launch_bounds__(256) void probe3_kernel(
    const float* __restrict__ rep0, const float* __restrict__ rep1,
    const float* __restrict__ rep2,
    const int* __restrict__ cnt,
    const float* __restrict__ brk, const int* __restrict__ bsk,
    const float* __restrict__ wtab,  // probe tables base (3 x TBL x 64)
    const float* __restrict__ pWl,   // (3,3,64,64); l0 slice per t
    const float* __restrict__ Wout,  // (64)
    float* __restrict__ out)         // (NP)
{
    __shared__ float tile[4][64];
    int c = threadIdx.x & 63;
    int w = threadIdx.x >> 6;
    int n = blockIdx.x * 4 + w;

    int m = min(cnt[n], CAP);
    float rvec = 0.0f; int svec = 0;
    if (c < m) { rvec = brk[(size_t)n * CAP + c]; svec = bsk[(size_t)n * CAP + c]; }
    float acc0 = 0.0f, acc1 = 0.0f, acc2 = 0.0f;
    const float scale = (float)TBL / RMAXT;
    const float* wt0 = wtab;
    const float* wt1 = wtab + (size_t)TBL * MUL;
    const float* wt2 = wtab + (size_t)2 * TBL * MUL;
#pragma unroll 2
    for (int p = 0; p < m; ++p) {
        float rr = lane_bcast_f(rvec, p);
        int sg = __builtin_amdgcn_readlane(svec, p);
        float x = fminf(rr * scale, (float)TBL - 1.001f);
        int i0 = (int)x;
        float f = x - (float)i0;
        size_t rowo = (size_t)i0 * MUL + c;
        float wv0 = fmaf(wt0[rowo + MUL] - wt0[rowo], f, wt0[rowo]);
        float wv1 = fmaf(wt1[rowo + MUL] - wt1[rowo], f, wt1[rowo]);
        float wv2 = fmaf(wt2[rowo + MUL] - wt2[rowo], f, wt2[rowo]);
        size_t so = (size_t)sg * MUL + c;
        acc0 = fmaf(rep0[so], wv0, acc0);
        acc1 = fmaf(rep1[so], wv1, acc1);
        acc2 = fmaf(rep2[so], wv2, acc2);
    }
    const float isk = 0.22360679774997896f;  // 1/sqrt(20)
    float res = 0.0f;
    float accs[3] = {acc0, acc1, acc2};
#pragma unroll
    for (int t = 0; t < 3; ++t) {
        tile[w][c] = accs[t] * isk;          // same-wave LDS RAW
        const float* W = pWl + (size_t)t * 3 * MUL * MUL;  // l0 slice
        float u = 0.0f;
#pragma unroll
        for (int k4 = 0; k4 < 16; ++k4) {
            float4 av = *(const float4*)&tile[w][k4 * 4];
            u = fmaf(av.x, W[(k4 * 4 + 0) * 64 + c], u);
            u = fmaf(av.y, W[(k4 * 4 + 1) * 64 + c], u);
            u = fmaf(av.z, W[(k4 * 4 + 2) * 64 + c], u);
            u = fmaf(av.w, W[(k4 * 4 + 3) * 64 + c], u);
        }
        res += silu_f(u);
    }

    float v = res * Wout[c];
#pragma unroll
    for (int o = 32; o > 0; o >>= 1) v += __shfl_down(v, o, 64);
    if (c == 0) out[n] = v;
}

// ---------------------------------------------------------------------------
extern "C" void kernel_launch(void* const* d_in, const int* in_sizes, int n_in,
                              void* d_out, int out_size, void* d_ws, size_t ws_size,
                              hipStream_t stream)
{
    const float* atom_xyz  = (const float*)d_in[0];
    const float* a_disp    = (const float*)d_in[1];
    const float* cell      = (const float*)d_in[2];
    const float* probe_xyz = (const float*)d_in[3];
    const float* p_disp    = (const float*)d_in[4];
    const float* W_embed   = (const float*)d_in[5];
    const float* Wr1       = (const float*)d_in[6];
    const float* br1       = (const float*)d_in[7];
    const float* Wr2       = (const float*)d_in[8];
    const float* br2       = (const float*)d_in[9];
    const float* Wl        = (const float*)d_in[10];
    const float* pWr1      = (const float*)d_in[12];
    const float* pbr1      = (const float*)d_in[13];
    const float* pWr2      = (const float*)d_in[14];
    const float* pbr2      = (const float*)d_in[15];
    const float* pWl       = (const float*)d_in[16];
    const float* W_out     = (const float*)d_in[18];
    const int*   atom_edges  = (const int*)d_in[19];
    const int*   probe_edges = (const int*)d_in[20];
    const int*   nodes       = (const int*)d_in[21];
    float* out = (float*)d_out;

    char* w = (char*)d_ws;
    auto alloc = [&](size_t bytes) -> void* {
        void* r = (void*)w;
        w += (bytes + 255) & ~(size_t)255;
        return r;
    };
    int*   cnt_both = (int*)alloc((size_t)(NA + NP) * 4);
    int*   cnt_a  = cnt_both;
    int*   cnt_p  = cnt_both + NA;
    float* br_a   = (float*)alloc((size_t)NA * CAP * 4);
    int*   bs_a   = (int*)alloc((size_t)NA * CAP * 4);
    float* br_p   = (float*)alloc((size_t)NP * CAP * 4);
    int*   bs_p   = (int*)alloc((size_t)NP * CAP * 4);
    float* h0row  = (float*)alloc((size_t)NA * MUL * 4);
    float* rep0   = (float*)alloc((size_t)NA * MUL * 4);
    float* rep1   = (float*)alloc((size_t)NA * MUL * 4);
    float* rep2   = (float*)alloc((size_t)NA * MUL * 4);
    float* wtab   = (float*)alloc((size_t)6 * TBL * MUL * 4);

    // 1) dep-free front-end: fused w-table + cnt zero + embedding
    front_kernel<<<TBLOCKS + ZBLOCKS + EBLOCKS, 256, 0, stream>>>(
        Wr1, pWr1, br1, pbr1, Wr2, pWr2, br2, pbr2,
        nodes, W_embed, cnt_both, h0row, wtab);

    // 2) geometry + bucket fill (replaces count/scan/geom chain)
    geom_kernel<<<(ET + PET + 255) / 256, 256, 0, stream>>>(
        atom_xyz, probe_xyz, atom_edges, probe_edges, a_disp, p_disp, cell,
        cnt_a, cnt_p, br_a, bs_a, br_p, bs_p);

    // 3-5) atom layers (sequential residual chain)
    const float* hprev = h0row;
    float* reps[3] = {rep0, rep1, rep2};
    for (int t = 0; t < Tc; ++t) {
        layer_kernel<<<NA / 4, 256, 0, stream>>>(
            hprev, reps[t], cnt_a, br_a, bs_a,
            wtab + (size_t)t * TBL * MUL,
            Wl + (size_t)t * 3 * MUL * MUL);
        hprev = reps[t];
    }

    // 6) fused probe layers + readout
    probe3_kernel<<<NP / 4, 256, 0, stream>>>(
        rep0, rep1, rep2, cnt_p, br_p, bs_p,
        wtab + (size_t)3 * TBL * MUL, pWl, W_out, out);
}